// Round 2
// baseline (458119.385 us; speedup 1.0000x reference)
//
#include <hip/hip_runtime.h>
#include <math.h>

// HierarchicalRecursiveTRM on MI355X — round 2.
// 8 teams x (2 batches, 32 WGs). Weights f32 in LDS (1/32 row-slice per WG).
// Team barrier: per-WG epoch flags (parallel release stores) + 32-lane poll,
// replacing the serialized atomic-counter RMW of round 1.

#define NB   16
#define SEQ  4096
#define TEAMS 8
#define WPT  32      // workgroups per team
#define BPT  2       // batches per team
#define NTH  256     // threads per workgroup

__device__ __forceinline__ float sigf(float v){ return 1.0f/(1.0f+expf(-v)); }

extern "C" __global__ __launch_bounds__(NTH, 1)
void trm_kernel(const float* __restrict__ x,   const float* __restrict__ h0,
                const float* __restrict__ wih, const float* __restrict__ whh,
                const float* __restrict__ bih, const float* __restrict__ bhh,
                const float* __restrict__ Lgw, const float* __restrict__ Lgb,
                const float* __restrict__ Ltw, const float* __restrict__ Ltb,
                const float* __restrict__ Luw, const float* __restrict__ Lub,
                const float* __restrict__ Hgw, const float* __restrict__ Hgb,
                const float* __restrict__ Htw, const float* __restrict__ Htb,
                const float* __restrict__ Huw, const float* __restrict__ Hub,
                float* __restrict__ out,
                unsigned* __restrict__ cnt_base, float* __restrict__ act_base)
{
  const int team = blockIdx.x & (TEAMS-1);   // XCD-local team (heuristic; correctness-independent)
  const int j    = blockIdx.x / TEAMS;       // 0..31 slice id within team
  const int tid  = threadIdx.x;

  // ---- LDS: weight slices (row stride 520: 520%32==8 -> 2-way=free) ----
  __shared__ float wgA[16][520];  // GRU r,z rows: [x(256) | h(256)]
  __shared__ float wgX[8][257];   // GRU n-gate, x part (w_ih rows 512..767)
  __shared__ float wgN[8][257];   // GRU n-gate, h part (w_hh rows 512..767)
  __shared__ float wcl[16][520];  // [Lg_w ; Lt_w] stacked rows
  __shared__ float wch[16][520];  // [Hg_w ; Ht_w] stacked rows
  __shared__ float wul[8][257];   // Lu_w rows
  __shared__ float wuh[8][257];   // Hu_w rows
  __shared__ float xst[BPT][256];
  __shared__ float st_o [BPT][256];
  __shared__ float st_zh[BPT][256];
  __shared__ float st_zl[BPT][256];
  __shared__ float st_h [BPT][256];
  __shared__ float bRZ[16], bX[8], bN[8], bCL[16], bCH[16], bUL[8], bUH[8];

  // ---------- one-time weight staging into LDS ----------
  {
    const int k = tid; // 0..255
    for (int r=0;r<16;r++){
      const int n = j*16+r;                 // 0..511
      wgA[r][k]     = wih[n*256+k];
      wgA[r][256+k] = whh[n*256+k];
      const float* sl = (n<256)? (Lgw + n*512) : (Ltw + (size_t)(n-256)*512);
      const float* sh = (n<256)? (Hgw + n*512) : (Htw + (size_t)(n-256)*512);
      wcl[r][k] = sl[k]; wcl[r][256+k] = sl[256+k];
      wch[r][k] = sh[k]; wch[r][256+k] = sh[256+k];
    }
    for (int r=0;r<8;r++){
      const int n = 512 + j*8 + r;
      wgX[r][k] = wih[n*256+k];
      wgN[r][k] = whh[n*256+k];
      const int u = j*8+r;
      wul[r][k] = Luw[u*256+k];
      wuh[r][k] = Huw[u*256+k];
    }
    if (tid<16){
      const int n = j*16+tid;
      bRZ[tid] = bih[n] + bhh[n];
      bCL[tid] = (n<256)? Lgb[n] : Ltb[n-256];
      bCH[tid] = (n<256)? Hgb[n] : Htb[n-256];
    }
    if (tid<8){
      bX[tid]  = bih[512 + j*8 + tid];
      bN[tid]  = bhh[512 + j*8 + tid];
      bUL[tid] = Lub[j*8+tid];
      bUH[tid] = Hub[j*8+tid];
    }
    for (int u=tid; u<BPT*256; u+=NTH){
      const int b=u>>8, i=u&255;
      st_h[b][i]  = h0[(team*BPT+b)*256+i];
      st_o[b][i]  = 0.f;
      st_zh[b][i] = 0.f;
      st_zl[b][i] = 0.f;
    }
  }
  __syncthreads();

  unsigned* flg  = cnt_base + team*64;                       // 32 flags, teams 256B apart
  float*    actT = act_base + (size_t)team*(2*BPT*1024);     // 2 alternating buffers
  unsigned  kst  = 0;                                        // global stage index

  // Flag barrier: parallel per-WG release stores + 32-lane acquire poll.
  auto barrier = [&](){
    __syncthreads();  // all waves' slice stores drained before the flag release
    if (tid < 64){
      const unsigned epoch = kst + 1u;
      if (tid == 0)
        __hip_atomic_store(flg + j, epoch, __ATOMIC_RELEASE, __HIP_MEMORY_SCOPE_AGENT);
      const int fl = tid & 31;
      for (;;){
        unsigned v = __hip_atomic_load(flg + fl, __ATOMIC_ACQUIRE, __HIP_MEMORY_SCOPE_AGENT);
        if (__all(v >= epoch)) break;
        __builtin_amdgcn_s_sleep(1);
      }
    }
    __syncthreads();
    kst++;
  };

  // C-cell stage: 16 rows/WG, K=512 = [o | hid]; then replicated gate update of o.
  auto cstage = [&](float (*W)[520], float* bC, float (*hid)[256], bool wout, int tt){
    __syncthreads();
    float* buf = actT + (kst&1u)*(BPT*1024);
    const int r = tid>>4, kk = tid&15;
    const float* wr = W[r];
    float a0=0.f, a1=0.f;
    #pragma unroll
    for (int i=0;i<16;i++){
      const float w = wr[kk+16*i];
      a0 += w*st_o[0][kk+16*i];
      a1 += w*st_o[1][kk+16*i];
    }
    #pragma unroll
    for (int i=0;i<16;i++){
      const float w = wr[256+kk+16*i];
      a0 += w*hid[0][kk+16*i];
      a1 += w*hid[1][kk+16*i];
    }
    a0 += __shfl_xor(a0,1); a0 += __shfl_xor(a0,2); a0 += __shfl_xor(a0,4); a0 += __shfl_xor(a0,8);
    a1 += __shfl_xor(a1,1); a1 += __shfl_xor(a1,2); a1 += __shfl_xor(a1,4); a1 += __shfl_xor(a1,8);
    if (kk==0){
      const int n = j*16+r;
      buf[n]      = a0 + bC[r];
      buf[1024+n] = a1 + bC[r];
    }
    barrier();
    for (int u=tid; u<BPT*256; u+=NTH){
      const int b=u>>8, i=u&255;
      const float g  = sigf(buf[b*1024+i]);
      const float rr = tanhf(buf[b*1024+256+i]);
      const float o  = g*rr + (1.f-g)*st_o[b][i];
      st_o[b][i] = o;
      if (wout) out[((size_t)(team*BPT+b)*SEQ + tt)*256 + i] = o;
    }
  };

  // U-cell stage: 8 rows/WG, K=256 over st_o; dst = tanh(pre).
  auto ustage = [&](float (*W)[257], float* bU, float (*dst)[256]){
    __syncthreads();
    float* buf = actT + (kst&1u)*(BPT*1024);
    const int r = tid>>5, kk = tid&31;
    const float* wr = W[r];
    float a0=0.f, a1=0.f;
    #pragma unroll
    for (int i=0;i<8;i++){
      const float w = wr[kk+32*i];
      a0 += w*st_o[0][kk+32*i];
      a1 += w*st_o[1][kk+32*i];
    }
    a0 += __shfl_xor(a0,1); a0 += __shfl_xor(a0,2); a0 += __shfl_xor(a0,4); a0 += __shfl_xor(a0,8); a0 += __shfl_xor(a0,16);
    a1 += __shfl_xor(a1,1); a1 += __shfl_xor(a1,2); a1 += __shfl_xor(a1,4); a1 += __shfl_xor(a1,8); a1 += __shfl_xor(a1,16);
    if (kk==0){
      const int n = j*8+r;
      buf[n]      = a0 + bU[r];
      buf[1024+n] = a1 + bU[r];
    }
    barrier();
    for (int u=tid; u<BPT*256; u+=NTH){
      const int b=u>>8, i=u&255;
      dst[b][i] = tanhf(buf[b*1024+i]);
    }
  };

  // x prefetch registers: thread tid holds xst[0][tid] and xst[1][tid] of step t.
  float px0 = x[((size_t)(team*BPT+0)*SEQ + 0)*256 + tid];
  float px1 = x[((size_t)(team*BPT+1)*SEQ + 0)*256 + tid];

  #pragma unroll 1
  for (int t=0; t<SEQ; ++t){
    // ---- stage 0: GRU (r,z combined; xn & hn separate for the r*hn term) ----
    __syncthreads();
    xst[0][tid] = px0;
    xst[1][tid] = px1;
    __syncthreads();
    {
      float* buf = actT + (kst&1u)*(BPT*1024);
      const int r = tid>>4, kk = tid&15;
      { // r,z rows: K=512 = [x | h], bias = b_ih + b_hh
        const float* wr = wgA[r];
        float a0=0.f, a1=0.f;
        #pragma unroll
        for (int i=0;i<16;i++){
          const float w = wr[kk+16*i];
          a0 += w*xst[0][kk+16*i];
          a1 += w*xst[1][kk+16*i];
        }
        #pragma unroll
        for (int i=0;i<16;i++){
          const float w = wr[256+kk+16*i];
          a0 += w*st_h[0][kk+16*i];
          a1 += w*st_h[1][kk+16*i];
        }
        a0 += __shfl_xor(a0,1); a0 += __shfl_xor(a0,2); a0 += __shfl_xor(a0,4); a0 += __shfl_xor(a0,8);
        a1 += __shfl_xor(a1,1); a1 += __shfl_xor(a1,2); a1 += __shfl_xor(a1,4); a1 += __shfl_xor(a1,8);
        if (kk==0){
          const int n=j*16+r;
          buf[n]      = a0 + bRZ[r];
          buf[1024+n] = a1 + bRZ[r];
        }
      }
      { // n-gate short rows: sr<8 -> xn (K=x), sr>=8 -> hn (K=h)
        const int sr = tid>>4;
        const float* wr = (sr<8)? wgX[sr] : wgN[sr-8];
        float (*src)[256] = (sr<8)? xst : st_h;
        float a0=0.f, a1=0.f;
        #pragma unroll
        for (int i=0;i<16;i++){
          const float w = wr[kk+16*i];
          a0 += w*src[0][kk+16*i];
          a1 += w*src[1][kk+16*i];
        }
        a0 += __shfl_xor(a0,1); a0 += __shfl_xor(a0,2); a0 += __shfl_xor(a0,4); a0 += __shfl_xor(a0,8);
        a1 += __shfl_xor(a1,1); a1 += __shfl_xor(a1,2); a1 += __shfl_xor(a1,4); a1 += __shfl_xor(a1,8);
        if (kk==0){
          const int nn = (sr<8)? (512 + j*8 + sr) : (768 + j*8 + (sr-8));
          const float bb = (sr<8)? bX[sr] : bN[sr-8];
          buf[nn]      = a0 + bb;
          buf[1024+nn] = a1 + bb;
        }
      }
      barrier();
      const bool last = (t==SEQ-1);
      for (int u=tid; u<BPT*256; u+=NTH){
        const int b=u>>8, i=u&255;
        const float pr = buf[b*1024 + i];
        const float pz = buf[b*1024 + 256 + i];
        const float xn = buf[b*1024 + 512 + i];
        const float hn = buf[b*1024 + 768 + i];
        const float rg = sigf(pr);
        const float zg = sigf(pz);
        const float ng = tanhf(xn + rg*hn);
        const float hv = (1.f-zg)*ng + zg*st_h[b][i];
        st_h[b][i] = hv;
        st_o[b][i] = hv;
        if (last) out[(size_t)NB*SEQ*256 + (team*BPT+b)*256 + i] = hv;
      }
      // prefetch x for step t+1 (latency hidden behind 12 refinement stages)
      if (t+1 < SEQ){
        px0 = x[((size_t)(team*BPT+0)*SEQ + (t+1))*256 + tid];
        px1 = x[((size_t)(team*BPT+1)*SEQ + (t+1))*256 + tid];
      }
    }
    // ---- refinement: 2 H-cycles of (3x L-cell, U_L, H-cell, U_H) ----
    #pragma unroll 1
    for (int c=0;c<2;c++){
      cstage(wcl,bCL,st_zh,false,t);
      cstage(wcl,bCL,st_zh,false,t);
      cstage(wcl,bCL,st_zh,false,t);
      ustage(wul,bUL,st_zl);
      cstage(wch,bCH,st_zl,(c==1),t);   // second H-cell output = refined[t]
      ustage(wuh,bUH,st_zh);
    }
  }
}

extern "C" void kernel_launch(void* const* d_in, const int* in_sizes, int n_in,
                              void* d_out, int out_size, void* d_ws, size_t ws_size,
                              hipStream_t stream)
{
  // ws layout: [0,4096): team flag arrays (256B apart). [4096, +128KB): activation buffers.
  hipMemsetAsync(d_ws, 0, 4096, stream);
  unsigned* cnt = (unsigned*)d_ws;
  float*    act = (float*)((char*)d_ws + 4096);

  dim3 grid(TEAMS*WPT), block(NTH);
  hipLaunchKernelGGL(trm_kernel, grid, block, 0, stream,
    (const float*)d_in[0],  (const float*)d_in[1],
    (const float*)d_in[2],  (const float*)d_in[3],
    (const float*)d_in[4],  (const float*)d_in[5],
    (const float*)d_in[6],  (const float*)d_in[7],
    (const float*)d_in[8],  (const float*)d_in[9],
    (const float*)d_in[10], (const float*)d_in[11],
    (const float*)d_in[12], (const float*)d_in[13],
    (const float*)d_in[14], (const float*)d_in[15],
    (const float*)d_in[16], (const float*)d_in[17],
    (float*)d_out, cnt, act);
}

// Round 3
// 145459.485 us; speedup vs baseline: 3.1495x; 3.1495x over previous
//
#include <hip/hip_runtime.h>
#include <math.h>

// HierarchicalRecursiveTRM on MI355X — round 3.
// 8 teams x (2 batches, 32 WGs). Weights f32 in LDS, rows [8j,8j+8) of every
// matrix per WG. Cross-WG exchange via RELAXED agent-scope atomics only
// (sc0/sc1 bypass loads/stores, NO cache-maintenance), ordered by
// s_waitcnt vmcnt(0) + __syncthreads before the relaxed flag store.

#define NB   16
#define SEQ  4096
#define TEAMS 8
#define WPT  32      // workgroups per team
#define BPT  2       // batches per team
#define NTH  256     // threads per workgroup

__device__ __forceinline__ float fexp(float v){ return __builtin_amdgcn_exp2f(v*1.44269504089f); }
__device__ __forceinline__ float sigf(float v){ return __builtin_amdgcn_rcpf(1.f + fexp(-v)); }
__device__ __forceinline__ float ftanh(float v){ return 2.f*sigf(2.f*v) - 1.f; }

__device__ __forceinline__ void st_u32(unsigned* p, unsigned v){
  __hip_atomic_store(p, v, __ATOMIC_RELAXED, __HIP_MEMORY_SCOPE_AGENT);
}
__device__ __forceinline__ unsigned ld_u32(const unsigned* p){
  return __hip_atomic_load(p, __ATOMIC_RELAXED, __HIP_MEMORY_SCOPE_AGENT);
}
__device__ __forceinline__ void st_f32(float* p, float v){
  __hip_atomic_store(p, v, __ATOMIC_RELAXED, __HIP_MEMORY_SCOPE_AGENT);
}
__device__ __forceinline__ float ld_f32(const float* p){
  return __hip_atomic_load(p, __ATOMIC_RELAXED, __HIP_MEMORY_SCOPE_AGENT);
}
__device__ __forceinline__ float2 ld_f32x2(const float* p){
  unsigned long long v = __hip_atomic_load((const unsigned long long*)p,
                                           __ATOMIC_RELAXED, __HIP_MEMORY_SCOPE_AGENT);
  union { unsigned long long u; float2 f; } c; c.u = v; return c.f;
}

extern "C" __global__ __launch_bounds__(NTH, 1)
void trm_kernel(const float* __restrict__ x,   const float* __restrict__ h0,
                const float* __restrict__ wih, const float* __restrict__ whh,
                const float* __restrict__ bih, const float* __restrict__ bhh,
                const float* __restrict__ Lgw, const float* __restrict__ Lgb,
                const float* __restrict__ Ltw, const float* __restrict__ Ltb,
                const float* __restrict__ Luw, const float* __restrict__ Lub,
                const float* __restrict__ Hgw, const float* __restrict__ Hgb,
                const float* __restrict__ Htw, const float* __restrict__ Htb,
                const float* __restrict__ Huw, const float* __restrict__ Hub,
                float* __restrict__ out,
                unsigned* __restrict__ flg_base, float* __restrict__ act_base)
{
  const int team = blockIdx.x & (TEAMS-1);
  const int j    = blockIdx.x / TEAMS;       // 0..31 slice id within team
  const int tid  = threadIdx.x;

  // ---- LDS (pads: 520%32==8, 264%32==8 -> 2 lanes/bank = free) ----
  __shared__ float wgRZ[16][520];  // rows 0..7: W_[ir|hr], rows 8..15: W_[iz|hz]
  __shared__ float wgX[8][264];    // W_in rows (x part of n-gate)
  __shared__ float wgN[8][264];    // W_hn rows (h part of n-gate)
  __shared__ float wclG[8][520], wclT[8][520];  // L-cell gate/tanh rows [o|hid]
  __shared__ float wchG[8][520], wchT[8][520];  // H-cell gate/tanh rows
  __shared__ float wul[8][264],  wuh[8][264];   // Lu/Hu rows
  __shared__ float xst [BPT][256];
  __shared__ float st_o [BPT][256];
  __shared__ float st_zh[BPT][256];
  __shared__ float st_zl[BPT][256];
  __shared__ float st_h [BPT][256];
  __shared__ float bR[8],bZ[8],bX[8],bN[8],bCLg[8],bCLt[8],bCHg[8],bCHt[8],bUL[8],bUH[8];

  // ---------- one-time weight staging ----------
  {
    const int k = tid;
    for (int r=0;r<8;r++){
      const int nr = j*8+r;
      wgRZ[r][k]       = wih[(size_t)nr*256+k];
      wgRZ[r][256+k]   = whh[(size_t)nr*256+k];
      wgRZ[8+r][k]     = wih[(size_t)(256+nr)*256+k];
      wgRZ[8+r][256+k] = whh[(size_t)(256+nr)*256+k];
      wgX[r][k] = wih[(size_t)(512+nr)*256+k];
      wgN[r][k] = whh[(size_t)(512+nr)*256+k];
      wclG[r][k] = Lgw[(size_t)nr*512+k];  wclG[r][256+k] = Lgw[(size_t)nr*512+256+k];
      wclT[r][k] = Ltw[(size_t)nr*512+k];  wclT[r][256+k] = Ltw[(size_t)nr*512+256+k];
      wchG[r][k] = Hgw[(size_t)nr*512+k];  wchG[r][256+k] = Hgw[(size_t)nr*512+256+k];
      wchT[r][k] = Htw[(size_t)nr*512+k];  wchT[r][256+k] = Htw[(size_t)nr*512+256+k];
      wul[r][k] = Luw[(size_t)nr*256+k];
      wuh[r][k] = Huw[(size_t)nr*256+k];
    }
    if (tid<8){
      const int nr = j*8+tid;
      bR[tid]  = bih[nr]     + bhh[nr];
      bZ[tid]  = bih[256+nr] + bhh[256+nr];
      bX[tid]  = bih[512+nr];
      bN[tid]  = bhh[512+nr];
      bCLg[tid]= Lgb[nr];  bCLt[tid]= Ltb[nr];
      bCHg[tid]= Hgb[nr];  bCHt[tid]= Htb[nr];
      bUL[tid] = Lub[nr];  bUH[tid] = Hub[nr];
    }
    for (int u=tid; u<BPT*256; u+=NTH){
      const int b=u>>8, i=u&255;
      st_h[b][i]  = h0[(team*BPT+b)*256+i];
      st_o[b][i]  = 0.f;
      st_zh[b][i] = 0.f;
      st_zl[b][i] = 0.f;
    }
  }
  __syncthreads();

  unsigned* flg  = flg_base + team*1024;                     // 4KB-separated flag arrays
  float*    actT = act_base + (size_t)team*8192;             // 32KB-separated buffers
  unsigned  kst  = 0;

  // Maintenance-free team barrier: vmcnt-drained relaxed stores + relaxed poll.
  auto barrier = [&](){
    asm volatile("s_waitcnt vmcnt(0)" ::: "memory");   // this wave's sc0sc1 stores visible
    __syncthreads();                                   // all waves drained
    if (tid < 64){
      const unsigned epoch = kst + 1u;
      if (tid == 0) st_u32(flg + j, epoch);
      const int fl = tid & 31;
      for (;;){
        unsigned v = ld_u32(flg + fl);
        if (__all(v >= epoch)) break;
        __builtin_amdgcn_s_sleep(1);
      }
    }
    asm volatile("" ::: "memory");
    __syncthreads();
    kst++;
  };

  // C-cell: WG owns rows [8j,8j+8): unit u<8 -> gate row, u>=8 -> tanh row. K=512=[o|hid].
  auto cstage = [&](float (*WG)[520], float (*WT)[520], float* bG, float* bT,
                    float (*hid)[256], bool wout, int tt){
    __syncthreads();
    float* buf = actT + (kst&1u)*(BPT*1024);
    const int u = tid>>4, kk = tid&15;
    const bool isT = (u>=8); const int r = u&7;
    const float* wr = isT? WT[r] : WG[r];
    float a0=0.f, a1=0.f;
    #pragma unroll
    for (int i=0;i<16;i++){
      const float w = wr[kk+16*i];
      a0 += w*st_o[0][kk+16*i];
      a1 += w*st_o[1][kk+16*i];
    }
    #pragma unroll
    for (int i=0;i<16;i++){
      const float w = wr[256+kk+16*i];
      a0 += w*hid[0][kk+16*i];
      a1 += w*hid[1][kk+16*i];
    }
    a0 += __shfl_xor(a0,1); a0 += __shfl_xor(a0,2); a0 += __shfl_xor(a0,4); a0 += __shfl_xor(a0,8);
    a1 += __shfl_xor(a1,1); a1 += __shfl_xor(a1,2); a1 += __shfl_xor(a1,4); a1 += __shfl_xor(a1,8);
    if (kk==0){
      const int n = j*8+r;
      const float bb = isT? bT[r] : bG[r];
      st_f32(&buf[2*n+isT],      a0 + bb);
      st_f32(&buf[1024+2*n+isT], a1 + bb);
    }
    barrier();
    for (int u2=tid; u2<BPT*256; u2+=NTH){
      const int b=u2>>8, i=u2&255;
      const float2 gt = ld_f32x2(&buf[b*1024 + 2*i]);
      const float g  = sigf(gt.x);
      const float rr = ftanh(gt.y);
      const float o  = g*rr + (1.f-g)*st_o[b][i];
      st_o[b][i] = o;
      if (wout) out[((size_t)(team*BPT+b)*SEQ + tt)*256 + i] = o;
    }
  };

  // U-cell: 8 rows/WG, 32-lane units, K=256 over st_o; dst = tanh(pre).
  auto ustage = [&](float (*W)[264], float* bU, float (*dst)[256]){
    __syncthreads();
    float* buf = actT + (kst&1u)*(BPT*1024);
    const int u = tid>>5, kk = tid&31;
    const float* wr = W[u];
    float a0=0.f, a1=0.f;
    #pragma unroll
    for (int i=0;i<8;i++){
      const float w = wr[kk+32*i];
      a0 += w*st_o[0][kk+32*i];
      a1 += w*st_o[1][kk+32*i];
    }
    a0 += __shfl_xor(a0,1); a0 += __shfl_xor(a0,2); a0 += __shfl_xor(a0,4); a0 += __shfl_xor(a0,8); a0 += __shfl_xor(a0,16);
    a1 += __shfl_xor(a1,1); a1 += __shfl_xor(a1,2); a1 += __shfl_xor(a1,4); a1 += __shfl_xor(a1,8); a1 += __shfl_xor(a1,16);
    if (kk==0){
      const int n = j*8+u;
      st_f32(&buf[n],      a0 + bU[u]);
      st_f32(&buf[1024+n], a1 + bU[u]);
    }
    barrier();
    for (int u2=tid; u2<BPT*256; u2+=NTH){
      const int b=u2>>8, i=u2&255;
      dst[b][i] = ftanh(ld_f32(&buf[b*1024+i]));
    }
  };

  float px0 = x[((size_t)(team*BPT+0)*SEQ + 0)*256 + tid];
  float px1 = x[((size_t)(team*BPT+1)*SEQ + 0)*256 + tid];

  #pragma unroll 1
  for (int t=0; t<SEQ; ++t){
    // ---- stage 0: GRU. pass1: r,z rows (K=512). pass2: xn,hn rows (K=256). ----
    __syncthreads();
    xst[0][tid] = px0;
    xst[1][tid] = px1;
    __syncthreads();
    {
      float* buf = actT + (kst&1u)*(BPT*1024);
      const int u = tid>>4, kk = tid&15;
      const int r = u&7;
      const int n = j*8+r;
      { // pass1: u<8 -> r-row, u>=8 -> z-row; K=512=[x|h]
        const bool isZ = (u>=8);
        const float* wr = wgRZ[u];
        float a0=0.f, a1=0.f;
        #pragma unroll
        for (int i=0;i<16;i++){
          const float w = wr[kk+16*i];
          a0 += w*xst[0][kk+16*i];
          a1 += w*xst[1][kk+16*i];
        }
        #pragma unroll
        for (int i=0;i<16;i++){
          const float w = wr[256+kk+16*i];
          a0 += w*st_h[0][kk+16*i];
          a1 += w*st_h[1][kk+16*i];
        }
        a0 += __shfl_xor(a0,1); a0 += __shfl_xor(a0,2); a0 += __shfl_xor(a0,4); a0 += __shfl_xor(a0,8);
        a1 += __shfl_xor(a1,1); a1 += __shfl_xor(a1,2); a1 += __shfl_xor(a1,4); a1 += __shfl_xor(a1,8);
        if (kk==0){
          const float bb = isZ? bZ[r] : bR[r];
          st_f32(&buf[4*n+isZ],      a0 + bb);
          st_f32(&buf[1024+4*n+isZ], a1 + bb);
        }
      }
      { // pass2: u<8 -> xn row (src=x), u>=8 -> hn row (src=h); K=256
        const bool isH = (u>=8);
        const float* wr = isH? wgN[r] : wgX[r];
        float (*src)[256] = isH? st_h : xst;
        float a0=0.f, a1=0.f;
        #pragma unroll
        for (int i=0;i<16;i++){
          const float w = wr[kk+16*i];
          a0 += w*src[0][kk+16*i];
          a1 += w*src[1][kk+16*i];
        }
        a0 += __shfl_xor(a0,1); a0 += __shfl_xor(a0,2); a0 += __shfl_xor(a0,4); a0 += __shfl_xor(a0,8);
        a1 += __shfl_xor(a1,1); a1 += __shfl_xor(a1,2); a1 += __shfl_xor(a1,4); a1 += __shfl_xor(a1,8);
        if (kk==0){
          const float bb = isH? bN[r] : bX[r];
          st_f32(&buf[4*n+2+isH],      a0 + bb);
          st_f32(&buf[1024+4*n+2+isH], a1 + bb);
        }
      }
      barrier();
      const bool last = (t==SEQ-1);
      for (int u2=tid; u2<BPT*256; u2+=NTH){
        const int b=u2>>8, i=u2&255;
        const float2 c0 = ld_f32x2(&buf[b*1024 + 4*i]);     // (pr, pz)
        const float2 c1 = ld_f32x2(&buf[b*1024 + 4*i + 2]); // (xn, hn)
        const float rg = sigf(c0.x);
        const float zg = sigf(c0.y);
        const float ng = ftanh(c1.x + rg*c1.y);
        const float hv = (1.f-zg)*ng + zg*st_h[b][i];
        st_h[b][i] = hv;
        st_o[b][i] = hv;
        if (last) out[(size_t)NB*SEQ*256 + (team*BPT+b)*256 + i] = hv;
      }
      if (t+1 < SEQ){
        px0 = x[((size_t)(team*BPT+0)*SEQ + (t+1))*256 + tid];
        px1 = x[((size_t)(team*BPT+1)*SEQ + (t+1))*256 + tid];
      }
    }
    // ---- refinement: 2 H-cycles of (3x L-cell, U_L, H-cell, U_H) ----
    #pragma unroll 1
    for (int c=0;c<2;c++){
      cstage(wclG,wclT,bCLg,bCLt,st_zh,false,t);
      cstage(wclG,wclT,bCLg,bCLt,st_zh,false,t);
      cstage(wclG,wclT,bCLg,bCLt,st_zh,false,t);
      ustage(wul,bUL,st_zl);
      cstage(wchG,wchT,bCHg,bCHt,st_zl,(c==1),t);   // 2nd H-cell output = refined[t]
      ustage(wuh,bUH,st_zh);
    }
  }
}

extern "C" void kernel_launch(void* const* d_in, const int* in_sizes, int n_in,
                              void* d_out, int out_size, void* d_ws, size_t ws_size,
                              hipStream_t stream)
{
  // ws layout: [0,32KB): team flag arrays (4KB apart). [64KB,+8x32KB): activation buffers.
  hipMemsetAsync(d_ws, 0, TEAMS*4096, stream);
  unsigned* flg = (unsigned*)d_ws;
  float*    act = (float*)((char*)d_ws + 65536);

  dim3 grid(TEAMS*WPT), block(NTH);
  hipLaunchKernelGGL(trm_kernel, grid, block, 0, stream,
    (const float*)d_in[0],  (const float*)d_in[1],
    (const float*)d_in[2],  (const float*)d_in[3],
    (const float*)d_in[4],  (const float*)d_in[5],
    (const float*)d_in[6],  (const float*)d_in[7],
    (const float*)d_in[8],  (const float*)d_in[9],
    (const float*)d_in[10], (const float*)d_in[11],
    (const float*)d_in[12], (const float*)d_in[13],
    (const float*)d_in[14], (const float*)d_in[15],
    (const float*)d_in[16], (const float*)d_in[17],
    (float*)d_out, flg, act);
}